// Round 1
// baseline (407.196 us; speedup 1.0000x reference)
//
#include <hip/hip_runtime.h>

typedef unsigned short u16;
typedef __bf16 bf16x8 __attribute__((ext_vector_type(8)));
typedef float f32x4 __attribute__((ext_vector_type(4)));
typedef u16 u16x8 __attribute__((ext_vector_type(8)));

#define T_TOK 2048
#define HID   1024
#define NEXP  32
#define IM    512
#define SI    2048
#define TOPK  6
#define PLAN_MAX 160

// exact RNE float->bf16
__device__ __forceinline__ u16 f2bf(float f){
  unsigned u = __float_as_uint(f);
  u += 0x7FFFu + ((u >> 16) & 1u);
  return (u16)(u >> 16);
}

// async global->LDS, 16B per lane. LDS dest must be wave-uniform base + lane*16.
__device__ __forceinline__ void gll16(const void* g, void* l){
  __builtin_amdgcn_global_load_lds((const __attribute__((address_space(1))) void*)g,
                                   (__attribute__((address_space(3))) void*)l, 16, 0, 0);
}

__device__ __forceinline__ u16x8 cvt2(float4 a, float4 b){
  u16x8 o;
  o[0] = f2bf(a.x); o[1] = f2bf(a.y); o[2] = f2bf(a.z); o[3] = f2bf(a.w);
  o[4] = f2bf(b.x); o[5] = f2bf(b.y); o[6] = f2bf(b.z); o[7] = f2bf(b.w);
  return o;
}

// big weights: upw (2097152 u16x8) | dnw (2097152 u16x8). 2 float4 loads -> one
// 16B store per thread (2x MLP, full-width stores).
__global__ __launch_bounds__(256) void cvt_big_kernel(const float4* __restrict__ s1,
                                                      const float4* __restrict__ s2,
                                                      u16x8* __restrict__ d1,
                                                      u16x8* __restrict__ d2){
  long i = (long)blockIdx.x * 256 + threadIdx.x;   // ushort8 index
  const float4* s; u16x8* d;
  if (i < 2097152L){ s = s1; d = d1; }
  else             { s = s2; d = d2; i -= 2097152L; }
  float4 a = s[2*i], b = s[2*i+1];
  d[i] = cvt2(a, b);
}

// small regions: x | supw | sdnw, each 262144 u16x8
__global__ __launch_bounds__(256) void cvt_small_kernel(const float4* __restrict__ s0,
                                                        const float4* __restrict__ s3,
                                                        const float4* __restrict__ s4,
                                                        u16x8* __restrict__ d0,
                                                        u16x8* __restrict__ d3,
                                                        u16x8* __restrict__ d4){
  long i = (long)blockIdx.x * 256 + threadIdx.x;
  const float4* s; u16x8* d;
  if      (i < 262144L){ s = s0; d = d0; }
  else if (i < 524288L){ s = s3; d = d3; i -= 262144L; }
  else                 { s = s4; d = d4; i -= 524288L; }
  float4 a = s[2*i], b = s[2*i+1];
  d[i] = cvt2(a, b);
}

// router: 4 tokens/block, 1 wave/token, all-register cross-lane top-k, NO atomics.
// writes dense per-token choices ce[t*6+k] (expert id), cw[t*6+k] (weight).
__global__ __launch_bounds__(256) void router_kernel(const float* __restrict__ x,
                                                     const float* __restrict__ gate,
                                                     const float* __restrict__ ebias,
                                                     int* __restrict__ ce,
                                                     float* __restrict__ cw){
  int wave = threadIdx.x >> 6;
  int lane = threadIdx.x & 63;
  int t = blockIdx.x * 4 + wave;
  int e = lane & 31, half = lane >> 5;
  const float4* xv = (const float4*)(x + (size_t)t * HID);
  const float4* gv = (const float4*)(gate + (size_t)e * HID);
  double d0 = 0, d1 = 0, d2 = 0, d3 = 0;
  for (int i = half * 128; i < half * 128 + 128; i++){
    float4 a = xv[i], b = gv[i];
    d0 += (double)a.x * b.x; d1 += (double)a.y * b.y;
    d2 += (double)a.z * b.z; d3 += (double)a.w * b.w;
  }
  double acc = (d0 + d1) + (d2 + d3);
  acc += __shfl_xor(acc, 32);
  double score = 1.0 / (1.0 + exp(-acc));
  double sc = score + (double)ebias[e];
  double o1  = __shfl_xor(sc, 1);
  double hi  = fmax(sc, o1), lo = fmin(sc, o1);
  double ohi = __shfl_xor(hi, 2), olo = __shfl_xor(lo, 2);
  double gs  = (hi >= ohi) ? hi + fmax(lo, ohi) : ohi + fmax(olo, hi);
  int g = e >> 2;
  int rank = 0;
#pragma unroll
  for (int j = 0; j < 8; j++){
    double gj = __shfl(gs, j * 4);
    if (gj > gs || (gj == gs && j < g)) rank++;
  }
  double cur = (rank < 4) ? sc : 0.0;
  int sel_e[TOPK]; double sel_w[TOPK]; double wsum = 0.0;
#pragma unroll
  for (int k = 0; k < TOPK; k++){
    double bv = cur; int bi = lane;
#pragma unroll
    for (int m = 32; m >= 1; m >>= 1){
      double ov = __shfl_xor(bv, m); int oi = __shfl_xor(bi, m);
      if (ov > bv || (ov == bv && oi < bi)) { bv = ov; bi = oi; }
    }
    if ((bi & 31) == e) cur = -1e300;
    double ws = __shfl(score, bi);
    sel_e[k] = bi; sel_w[k] = ws; wsum += ws;
  }
  double scale = 2.5 / (wsum + 1e-20);
#pragma unroll
  for (int k = 0; k < TOPK; k++){
    if (lane == k){                       // compile-time idx -> no scratch spill
      ce[t * TOPK + k] = sel_e[k] & 31;
      cw[t * TOPK + k] = (float)(sel_w[k] * scale);
    }
  }
}

// 32 blocks (one per expert): ordered compaction of the 12288 choices into
// per-expert token lists via ballot prefix scan. Deterministic, token-sorted.
__global__ __launch_bounds__(256) void build_kernel(const int* __restrict__ ce,
                                                    const float* __restrict__ cw,
                                                    int* __restrict__ cnt,
                                                    int* __restrict__ tok,
                                                    float* __restrict__ wl){
  int e = blockIdx.x;
  int tid = threadIdx.x, lane = tid & 63, wave = tid >> 6;
  __shared__ int wsum[4];
  int running = 0;
  for (int base = 0; base < T_TOK * TOPK; base += 256){
    int i = base + tid;                       // 12288 = 48*256, no bounds check
    bool m = (ce[i] == e);
    unsigned long long bal = __ballot(m);
    int woff = __popcll(bal & ((1ull << lane) - 1ull));
    if (lane == 0) wsum[wave] = __popcll(bal);
    __syncthreads();
    int wbase = 0;
#pragma unroll
    for (int wv = 0; wv < 4; wv++) if (wv < wave) wbase += wsum[wv];
    int btot = wsum[0] + wsum[1] + wsum[2] + wsum[3];
    if (m){
      int t = i / TOPK, k = i - t * TOPK;
      int pos = running + wbase + woff;
      tok[e * T_TOK + pos] = (t << 3) | k;
      wl[e * T_TOK + pos] = cw[i];
    }
    running += btot;
    __syncthreads();                          // wsum WAR hazard for next iter
  }
  if (tid == 0) cnt[e] = running;
}

// build dense tile plan: plan[1+i] = (tile_base<<8)|expert for every active 128-token tile
__global__ __launch_bounds__(256) void plan_kernel(const int* __restrict__ cnt,
                                                   int* __restrict__ plan){
  int tid = threadIdx.x;
  if (tid < PLAN_MAX) plan[1 + tid] = -1;
  __syncthreads();
  if (tid == 0){
    int n = 0;
    for (int e = 0; e < NEXP; e++){
      int c = cnt[e];
      for (int tb = 0; tb < c; tb += 128) plan[1 + n++] = (tb << 8) | e;
    }
    plan[0] = n;
  }
}

// ---- m97-style core: 128x128 block tile, BK=32, 4 waves in 2x2, 4x4 MFMA acc/wave ----
__device__ __forceinline__ void gemm_core(
    const char* gA0, const char* gA1, const char* gB0, const char* gB1,
    u16* lA, u16* lB, int iters, int tid, int wrow, int wcol, int quad, int l16,
    f32x4 acc[4][4])
{
  char* dA0 = (char*)lA + tid*16;
  char* dA1 = (char*)lA + 4096 + tid*16;
  char* dB0 = (char*)lB + tid*16;
  char* dB1 = (char*)lB + 4096 + tid*16;
  for (int it = 0; it < iters; ++it){
    gll16(gA0, dA0); gll16(gA1, dA1);
    gll16(gB0, dB0); gll16(gB1, dB1);
    gA0 += 64; gA1 += 64; gB0 += 64; gB1 += 64;
    __syncthreads();
    bf16x8 af[4], bfr[4];
#pragma unroll
    for (int mt = 0; mt < 4; mt++) af[mt] = *(const bf16x8*)&lA[(wrow + mt*16 + l16)*32 + quad*8];
#pragma unroll
    for (int nt = 0; nt < 4; nt++) bfr[nt] = *(const bf16x8*)&lB[(wcol + nt*16 + l16)*32 + quad*8];
#pragma unroll
    for (int mt = 0; mt < 4; mt++)
#pragma unroll
      for (int nt = 0; nt < 4; nt++)
        acc[mt][nt] = __builtin_amdgcn_mfma_f32_16x16x32_bf16(af[mt], bfr[nt], acc[mt][nt], 0, 0, 0);
    __syncthreads();
  }
}

#define ACC_INIT f32x4 acc[4][4]; \
  _Pragma("unroll") for (int i_ = 0; i_ < 4; i_++) \
  _Pragma("unroll") for (int j_ = 0; j_ < 4; j_++) acc[i_][j_] = (f32x4){0.f,0.f,0.f,0.f};

// shared up: C[2048][2048] = bf16(relu2(X[2048][1024] . W[2048][1024]^T))
__global__ __launch_bounds__(256) void sh_up_kernel(const u16* __restrict__ A,
                                                    const u16* __restrict__ B,
                                                    u16* __restrict__ C){
  __shared__ u16 lA[128*32], lB[128*32];
  int tid = threadIdx.x;
  int bm = blockIdx.x*128, bn = blockIdx.y*128;
  int lane = tid & 63, wave = tid >> 6, quad = lane >> 4, l16 = lane & 15;
  int wrow = (wave >> 1)*64, wcol = (wave & 1)*64;
  int srow = tid >> 2, sseg = (tid & 3)*16;
  const char* gA0 = (const char*)(A + (size_t)(bm + srow)*HID) + sseg;
  const char* gA1 = (const char*)(A + (size_t)(bm + 64 + srow)*HID) + sseg;
  const char* gB0 = (const char*)(B + (size_t)(bn + srow)*HID) + sseg;
  const char* gB1 = (const char*)(B + (size_t)(bn + 64 + srow)*HID) + sseg;
  ACC_INIT;
  gemm_core(gA0, gA1, gB0, gB1, lA, lB, HID/32, tid, wrow, wcol, quad, l16, acc);
#pragma unroll
  for (int mt = 0; mt < 4; mt++)
#pragma unroll
    for (int nt = 0; nt < 4; nt++)
#pragma unroll
      for (int r = 0; r < 4; r++){
        int m = bm + wrow + mt*16 + quad*4 + r;
        int n = bn + wcol + nt*16 + l16;
        float v = acc[mt][nt][r]; v = fmaxf(v, 0.f); v *= v;
        C[(size_t)m*SI + n] = f2bf(v);
      }
}

// shared down: out[2048][1024] = H[2048][2048] . W[1024][2048]^T (fp32)
__global__ __launch_bounds__(256) void sh_down_kernel(const u16* __restrict__ A,
                                                      const u16* __restrict__ B,
                                                      float* __restrict__ C){
  __shared__ u16 lA[128*32], lB[128*32];
  int tid = threadIdx.x;
  int bm = blockIdx.x*128, bn = blockIdx.y*128;
  int lane = tid & 63, wave = tid >> 6, quad = lane >> 4, l16 = lane & 15;
  int wrow = (wave >> 1)*64, wcol = (wave & 1)*64;
  int srow = tid >> 2, sseg = (tid & 3)*16;
  const char* gA0 = (const char*)(A + (size_t)(bm + srow)*SI) + sseg;
  const char* gA1 = (const char*)(A + (size_t)(bm + 64 + srow)*SI) + sseg;
  const char* gB0 = (const char*)(B + (size_t)(bn + srow)*SI) + sseg;
  const char* gB1 = (const char*)(B + (size_t)(bn + 64 + srow)*SI) + sseg;
  ACC_INIT;
  gemm_core(gA0, gA1, gB0, gB1, lA, lB, SI/32, tid, wrow, wcol, quad, l16, acc);
#pragma unroll
  for (int mt = 0; mt < 4; mt++)
#pragma unroll
    for (int nt = 0; nt < 4; nt++)
#pragma unroll
      for (int r = 0; r < 4; r++){
        int m = bm + wrow + mt*16 + quad*4 + r;
        int n = bn + wcol + nt*16 + l16;
        C[(size_t)m*HID + n] = acc[mt][nt][r];
      }
}

// expert up: hws[t*6+k][512] = bf16(relu2(x_t . up_e^T) * w)
__global__ __launch_bounds__(256) void expert_up_kernel(const u16* __restrict__ xb,
                                                        const u16* __restrict__ upb,
                                                        const int* __restrict__ cnt,
                                                        const int* __restrict__ tok,
                                                        const float* __restrict__ wl,
                                                        const int* __restrict__ plan,
                                                        u16* __restrict__ hws){
  int pv = plan[1 + blockIdx.x];
  if (pv < 0) return;
  int e = pv & 255;
  int tb = pv >> 8;
  int c = cnt[e];
  int bn = blockIdx.y * 128;
  const int* tl = tok + e * T_TOK;
  const float* wle = wl + e * T_TOK;
  __shared__ u16 lA[128*32], lB[128*32];
  int tid = threadIdx.x;
  int lane = tid & 63, wave = tid >> 6, quad = lane >> 4, l16 = lane & 15;
  int wrow = (wave >> 1)*64, wcol = (wave & 1)*64;
  int srow = tid >> 2, sseg = (tid & 3)*16;
  int s0 = tb + srow;      if (s0 > c-1) s0 = c-1;
  int s1 = tb + 64 + srow; if (s1 > c-1) s1 = c-1;
  int t0 = tl[s0] >> 3, t1 = tl[s1] >> 3;
  const char* gA0 = (const char*)(xb + (size_t)t0*HID) + sseg;
  const char* gA1 = (const char*)(xb + (size_t)t1*HID) + sseg;
  const u16* Bb = upb + (size_t)e * IM * HID;
  const char* gB0 = (const char*)(Bb + (size_t)(bn + srow)*HID) + sseg;
  const char* gB1 = (const char*)(Bb + (size_t)(bn + 64 + srow)*HID) + sseg;
  ACC_INIT;
  gemm_core(gA0, gA1, gB0, gB1, lA, lB, HID/32, tid, wrow, wcol, quad, l16, acc);
#pragma unroll
  for (int mt = 0; mt < 4; mt++)
#pragma unroll
    for (int r = 0; r < 4; r++){
      int s = tb + wrow + mt*16 + quad*4 + r;
      if (s < c){
        int code = tl[s];
        float w = wle[s];
        size_t hb = ((size_t)(code >> 3) * TOPK + (code & 7)) * IM;
#pragma unroll
        for (int nt = 0; nt < 4; nt++){
          float v = acc[mt][nt][r]; v = fmaxf(v, 0.f); v = v * v * w;
          hws[hb + bn + wcol + nt*16 + l16] = f2bf(v);
        }
      }
    }
}

// expert down: out[t][h] += h_slot . down_e^T  (fused reduce: one unsafeAtomicAdd
// per (slot,h); each output element receives <=6 adds on top of sh_down's store)
__global__ __launch_bounds__(256) void expert_down_kernel(const u16* __restrict__ hws,
                                                          const u16* __restrict__ dnb,
                                                          const int* __restrict__ cnt,
                                                          const int* __restrict__ tok,
                                                          const int* __restrict__ plan,
                                                          float* __restrict__ out){
  int pv = plan[1 + blockIdx.x];
  if (pv < 0) return;
  int e = pv & 255;
  int tb = pv >> 8;
  int c = cnt[e];
  int bn = blockIdx.y * 128;
  const int* tl = tok + e * T_TOK;
  __shared__ u16 lA[128*32], lB[128*32];
  int tid = threadIdx.x;
  int lane = tid & 63, wave = tid >> 6, quad = lane >> 4, l16 = lane & 15;
  int wrow = (wave >> 1)*64, wcol = (wave & 1)*64;
  int srow = tid >> 2, sseg = (tid & 3)*16;
  int s0 = tb + srow;      if (s0 > c-1) s0 = c-1;
  int s1 = tb + 64 + srow; if (s1 > c-1) s1 = c-1;
  int c0 = tl[s0], c1 = tl[s1];
  const char* gA0 = (const char*)(hws + ((size_t)(c0 >> 3)*TOPK + (c0 & 7))*IM) + sseg;
  const char* gA1 = (const char*)(hws + ((size_t)(c1 >> 3)*TOPK + (c1 & 7))*IM) + sseg;
  const u16* Bb = dnb + (size_t)e * HID * IM;
  const char* gB0 = (const char*)(Bb + (size_t)(bn + srow)*IM) + sseg;
  const char* gB1 = (const char*)(Bb + (size_t)(bn + 64 + srow)*IM) + sseg;
  ACC_INIT;
  gemm_core(gA0, gA1, gB0, gB1, lA, lB, IM/32, tid, wrow, wcol, quad, l16, acc);
#pragma unroll
  for (int mt = 0; mt < 4; mt++)
#pragma unroll
    for (int r = 0; r < 4; r++){
      int s = tb + wrow + mt*16 + quad*4 + r;
      if (s < c){
        int code = tl[s];
        float* ob = out + (size_t)(code >> 3) * HID;
#pragma unroll
        for (int nt = 0; nt < 4; nt++)
          unsafeAtomicAdd(&ob[bn + wcol + nt*16 + l16], acc[mt][nt][r]);
      }
    }
}

extern "C" void kernel_launch(void* const* d_in, const int* in_sizes, int n_in,
                              void* d_out, int out_size, void* d_ws, size_t ws_size,
                              hipStream_t stream) {
  const float* x    = (const float*)d_in[0];
  const float* gate = (const float*)d_in[1];
  const float* eb   = (const float*)d_in[2];
  const float* upw  = (const float*)d_in[3];
  const float* dnw  = (const float*)d_in[4];
  const float* supw = (const float*)d_in[5];
  const float* sdnw = (const float*)d_in[6];
  float* out = (float*)d_out;

  char* w = (char*)d_ws;
  size_t o = 0;
  int*   cnt  = (int*)(w + o);   o += 1024;
  int*   plan = (int*)(w + o);   o += 1024;
  int*   ce   = (int*)(w + o);   o += (size_t)T_TOK * TOPK * 4;
  float* cw   = (float*)(w + o); o += (size_t)T_TOK * TOPK * 4;
  int*   tok  = (int*)(w + o);   o += (size_t)NEXP * T_TOK * 4;
  float* wl   = (float*)(w + o); o += (size_t)NEXP * T_TOK * 4;
  u16*   xb   = (u16*)(w + o);   o += (size_t)T_TOK * HID * 2;
  u16*   dnb  = (u16*)(w + o);   o += (size_t)NEXP * HID * IM * 2;
  u16*   hws  = (u16*)(w + o);   o += (size_t)T_TOK * TOPK * IM * 2;
  u16*   upb  = (u16*)(w + o);   o += (size_t)NEXP * IM * HID * 2;   // 32MB
  u16*   supb = (u16*)(w + o);   o += (size_t)SI * HID * 2;          // 8MB
  u16*   sdnb = (u16*)(w + o);   o += (size_t)HID * SI * 2;          // 8MB
  u16*   shh  = (u16*)(w + o);   o += (size_t)T_TOK * SI * 2;        // 8MB

  // conversion: big weights (upw|dnw), then small (x|supw|sdnw)
  cvt_big_kernel<<<16384, 256, 0, stream>>>(
      (const float4*)upw, (const float4*)dnw, (u16x8*)upb, (u16x8*)dnb);
  cvt_small_kernel<<<3072, 256, 0, stream>>>(
      (const float4*)x, (const float4*)supw, (const float4*)sdnw,
      (u16x8*)xb, (u16x8*)supb, (u16x8*)sdnb);

  router_kernel<<<T_TOK/4, 256, 0, stream>>>(x, gate, eb, ce, cw);
  build_kernel<<<NEXP, 256, 0, stream>>>(ce, cw, cnt, tok, wl);
  plan_kernel<<<1, 256, 0, stream>>>(cnt, plan);

  sh_up_kernel<<<dim3(T_TOK/128, SI/128), 256, 0, stream>>>(xb, supb, shh);
  sh_down_kernel<<<dim3(T_TOK/128, HID/128), 256, 0, stream>>>(shh, sdnb, out);

  expert_up_kernel<<<dim3(PLAN_MAX, IM/128), 256, 0, stream>>>(xb, upb, cnt, tok, wl, plan, hws);
  expert_down_kernel<<<dim3(PLAN_MAX, HID/128), 256, 0, stream>>>(hws, dnb, cnt, tok, plan, out);
}

// Round 2
// 369.627 us; speedup vs baseline: 1.1016x; 1.1016x over previous
//
#include <hip/hip_runtime.h>

typedef unsigned short u16;
typedef __bf16 bf16x8 __attribute__((ext_vector_type(8)));
typedef float f32x4 __attribute__((ext_vector_type(4)));
typedef u16 u16x8 __attribute__((ext_vector_type(8)));

#define T_TOK 2048
#define HID   1024
#define NEXP  32
#define IM    512
#define SI    2048
#define TOPK  6
#define PLAN_MAX 160

// exact RNE float->bf16
__device__ __forceinline__ u16 f2bf(float f){
  unsigned u = __float_as_uint(f);
  u += 0x7FFFu + ((u >> 16) & 1u);
  return (u16)(u >> 16);
}

// async global->LDS, 16B per lane. LDS dest must be wave-uniform base + lane*16.
__device__ __forceinline__ void gll16(const void* g, void* l){
  __builtin_amdgcn_global_load_lds((const __attribute__((address_space(1))) void*)g,
                                   (__attribute__((address_space(3))) void*)l, 16, 0, 0);
}

__device__ __forceinline__ u16x8 cvt2(float4 a, float4 b){
  u16x8 o;
  o[0] = f2bf(a.x); o[1] = f2bf(a.y); o[2] = f2bf(a.z); o[3] = f2bf(a.w);
  o[4] = f2bf(b.x); o[5] = f2bf(b.y); o[6] = f2bf(b.z); o[7] = f2bf(b.w);
  return o;
}

// big weights: upw (2097152 u16x8) | dnw (2097152 u16x8)
__global__ __launch_bounds__(256) void cvt_big_kernel(const float4* __restrict__ s1,
                                                      const float4* __restrict__ s2,
                                                      u16x8* __restrict__ d1,
                                                      u16x8* __restrict__ d2){
  long i = (long)blockIdx.x * 256 + threadIdx.x;   // ushort8 index
  const float4* s; u16x8* d;
  if (i < 2097152L){ s = s1; d = d1; }
  else             { s = s2; d = d2; i -= 2097152L; }
  float4 a = s[2*i], b = s[2*i+1];
  d[i] = cvt2(a, b);
}

// fused: router (blocks 0..511) + small-region cvt x|supw|sdnw (blocks 512..3583)
__global__ __launch_bounds__(256) void cvt_small_router_kernel(
    const float* __restrict__ x, const float4* __restrict__ s3, const float4* __restrict__ s4,
    const float* __restrict__ gate, const float* __restrict__ ebias,
    u16x8* __restrict__ d0, u16x8* __restrict__ d3, u16x8* __restrict__ d4,
    int* __restrict__ ce, float* __restrict__ cw){
  int blk = blockIdx.x;
  if (blk >= 512){
    long i = (long)(blk - 512) * 256 + threadIdx.x;
    const float4* s; u16x8* d;
    if      (i < 262144L){ s = (const float4*)x; d = d0; }
    else if (i < 524288L){ s = s3; d = d3; i -= 262144L; }
    else                 { s = s4; d = d4; i -= 524288L; }
    float4 a = s[2*i], b = s[2*i+1];
    d[i] = cvt2(a, b);
    return;
  }
  // ---- router: 4 tokens/block, 1 wave/token, register cross-lane top-k ----
  int wave = threadIdx.x >> 6;
  int lane = threadIdx.x & 63;
  int t = blk * 4 + wave;
  int e = lane & 31, half = lane >> 5;
  const float4* xv = (const float4*)(x + (size_t)t * HID);
  const float4* gv = (const float4*)(gate + (size_t)e * HID);
  double d0a = 0, d1a = 0, d2a = 0, d3a = 0;
  for (int i = half * 128; i < half * 128 + 128; i++){
    float4 a = xv[i], b = gv[i];
    d0a += (double)a.x * b.x; d1a += (double)a.y * b.y;
    d2a += (double)a.z * b.z; d3a += (double)a.w * b.w;
  }
  double acc = (d0a + d1a) + (d2a + d3a);
  acc += __shfl_xor(acc, 32);
  double score = 1.0 / (1.0 + exp(-acc));
  double sc = score + (double)ebias[e];
  double o1  = __shfl_xor(sc, 1);
  double hi  = fmax(sc, o1), lo = fmin(sc, o1);
  double ohi = __shfl_xor(hi, 2), olo = __shfl_xor(lo, 2);
  double gs  = (hi >= ohi) ? hi + fmax(lo, ohi) : ohi + fmax(olo, hi);
  int g = e >> 2;
  int rank = 0;
#pragma unroll
  for (int j = 0; j < 8; j++){
    double gj = __shfl(gs, j * 4);
    if (gj > gs || (gj == gs && j < g)) rank++;
  }
  double cur = (rank < 4) ? sc : 0.0;
  int sel_e[TOPK]; double sel_w[TOPK]; double wsum = 0.0;
#pragma unroll
  for (int k = 0; k < TOPK; k++){
    double bv = cur; int bi = lane;
#pragma unroll
    for (int m = 32; m >= 1; m >>= 1){
      double ov = __shfl_xor(bv, m); int oi = __shfl_xor(bi, m);
      if (ov > bv || (ov == bv && oi < bi)) { bv = ov; bi = oi; }
    }
    if ((bi & 31) == e) cur = -1e300;
    double ws = __shfl(score, bi);
    sel_e[k] = bi; sel_w[k] = ws; wsum += ws;
  }
  double scale = 2.5 / (wsum + 1e-20);
#pragma unroll
  for (int k = 0; k < TOPK; k++){
    if (lane == k){                       // compile-time idx -> no scratch spill
      ce[t * TOPK + k] = sel_e[k] & 31;
      cw[t * TOPK + k] = (float)(sel_w[k] * scale);
    }
  }
}

// 32 blocks (one per expert): ordered compaction via ballot prefix scan.
__global__ __launch_bounds__(256) void build_kernel(const int* __restrict__ ce,
                                                    const float* __restrict__ cw,
                                                    int* __restrict__ cnt,
                                                    int* __restrict__ tok,
                                                    float* __restrict__ wl){
  int e = blockIdx.x;
  int tid = threadIdx.x, lane = tid & 63, wave = tid >> 6;
  __shared__ int wsum[4];
  int running = 0;
  for (int base = 0; base < T_TOK * TOPK; base += 256){
    int i = base + tid;                       // 12288 = 48*256, no bounds check
    bool m = (ce[i] == e);
    unsigned long long bal = __ballot(m);
    int woff = __popcll(bal & ((1ull << lane) - 1ull));
    if (lane == 0) wsum[wave] = __popcll(bal);
    __syncthreads();
    int wbase = 0;
#pragma unroll
    for (int wv = 0; wv < 4; wv++) if (wv < wave) wbase += wsum[wv];
    int btot = wsum[0] + wsum[1] + wsum[2] + wsum[3];
    if (m){
      int t = i / TOPK, k = i - t * TOPK;
      int pos = running + wbase + woff;
      tok[e * T_TOK + pos] = (t << 3) | k;
      wl[e * T_TOK + pos] = cw[i];
    }
    running += btot;
    __syncthreads();                          // wsum WAR hazard for next iter
  }
  if (tid == 0) cnt[e] = running;
}

// dense tile plan: plan[1+i] = (tile_base<<8)|expert for every active 128-token tile
__global__ __launch_bounds__(256) void plan_kernel(const int* __restrict__ cnt,
                                                   int* __restrict__ plan){
  int tid = threadIdx.x;
  if (tid < PLAN_MAX) plan[1 + tid] = -1;
  __syncthreads();
  if (tid == 0){
    int n = 0;
    for (int e = 0; e < NEXP; e++){
      int c = cnt[e];
      for (int tb = 0; tb < c; tb += 128) plan[1 + n++] = (tb << 8) | e;
    }
    plan[0] = n;
  }
}

// ---- 128x128 tile, BK=32, double-buffered LDS (T3-min 2-phase):
// issue next-tile global_load_lds into buf^1 BEFORE computing buf, one
// __syncthreads (vmcnt drain) per K-step -> load latency hides under MFMA.
__device__ __forceinline__ void gemm_core(
    const char* gA0, const char* gA1, const char* gB0, const char* gB1,
    u16* lA, u16* lB, int iters, int tid, int wrow, int wcol, int quad, int l16,
    f32x4 acc[4][4])
{
  char* bA = (char*)lA + tid*16;
  char* bB = (char*)lB + tid*16;
  // prologue: stage tile 0 into buffer 0
  gll16(gA0, bA);  gll16(gA1, bA + 4096);
  gll16(gB0, bB);  gll16(gB1, bB + 4096);
  gA0 += 64; gA1 += 64; gB0 += 64; gB1 += 64;
  __syncthreads();
  unsigned cur = 0;
  for (int it = 0; it < iters - 1; ++it){
    unsigned nxt = cur ^ 1;
    // prefetch next K-tile (in flight during this tile's compute)
    gll16(gA0, bA + nxt*8192);  gll16(gA1, bA + nxt*8192 + 4096);
    gll16(gB0, bB + nxt*8192);  gll16(gB1, bB + nxt*8192 + 4096);
    gA0 += 64; gA1 += 64; gB0 += 64; gB1 += 64;
    const u16* rA = lA + cur*4096;
    const u16* rB = lB + cur*4096;
    bf16x8 af[4], bfr[4];
#pragma unroll
    for (int mt = 0; mt < 4; mt++) af[mt]  = *(const bf16x8*)&rA[(wrow + mt*16 + l16)*32 + quad*8];
#pragma unroll
    for (int nt = 0; nt < 4; nt++) bfr[nt] = *(const bf16x8*)&rB[(wcol + nt*16 + l16)*32 + quad*8];
#pragma unroll
    for (int mt = 0; mt < 4; mt++)
#pragma unroll
      for (int nt = 0; nt < 4; nt++)
        acc[mt][nt] = __builtin_amdgcn_mfma_f32_16x16x32_bf16(af[mt], bfr[nt], acc[mt][nt], 0, 0, 0);
    __syncthreads();          // drains prefetch vmcnt + protects buf reuse
    cur = nxt;
  }
  const u16* rA = lA + cur*4096;
  const u16* rB = lB + cur*4096;
  bf16x8 af[4], bfr[4];
#pragma unroll
  for (int mt = 0; mt < 4; mt++) af[mt]  = *(const bf16x8*)&rA[(wrow + mt*16 + l16)*32 + quad*8];
#pragma unroll
  for (int nt = 0; nt < 4; nt++) bfr[nt] = *(const bf16x8*)&rB[(wcol + nt*16 + l16)*32 + quad*8];
#pragma unroll
  for (int mt = 0; mt < 4; mt++)
#pragma unroll
    for (int nt = 0; nt < 4; nt++)
      acc[mt][nt] = __builtin_amdgcn_mfma_f32_16x16x32_bf16(af[mt], bfr[nt], acc[mt][nt], 0, 0, 0);
}

#define ACC_INIT f32x4 acc[4][4]; \
  _Pragma("unroll") for (int i_ = 0; i_ < 4; i_++) \
  _Pragma("unroll") for (int j_ = 0; j_ < 4; j_++) acc[i_][j_] = (f32x4){0.f,0.f,0.f,0.f};

// fused A: blocks [0,256) shared-up, [256,896) expert-up. Both independent after plan.
__global__ __launch_bounds__(256) void up_fused_kernel(
    const u16* __restrict__ xb, const u16* __restrict__ supb, const u16* __restrict__ upb,
    const int* __restrict__ cnt, const int* __restrict__ tok, const float* __restrict__ wl,
    const int* __restrict__ plan, u16* __restrict__ shh, u16* __restrict__ hws){
  __shared__ u16 lA[2*128*32], lB[2*128*32];
  int tid = threadIdx.x;
  int lane = tid & 63, wave = tid >> 6, quad = lane >> 4, l16 = lane & 15;
  int wrow = (wave >> 1)*64, wcol = (wave & 1)*64;
  int srow = tid >> 2, sseg = (tid & 3)*16;
  int blk = blockIdx.x;
  if (blk < 256){
    // shared up: shh[2048][2048] = bf16(relu2(X . supW^T))
    int bm = (blk >> 4) * 128, bn = (blk & 15) * 128;
    const char* gA0 = (const char*)(xb + (size_t)(bm + srow)*HID) + sseg;
    const char* gA1 = (const char*)(xb + (size_t)(bm + 64 + srow)*HID) + sseg;
    const char* gB0 = (const char*)(supb + (size_t)(bn + srow)*HID) + sseg;
    const char* gB1 = (const char*)(supb + (size_t)(bn + 64 + srow)*HID) + sseg;
    ACC_INIT;
    gemm_core(gA0, gA1, gB0, gB1, lA, lB, HID/32, tid, wrow, wcol, quad, l16, acc);
#pragma unroll
    for (int mt = 0; mt < 4; mt++)
#pragma unroll
      for (int nt = 0; nt < 4; nt++)
#pragma unroll
        for (int r = 0; r < 4; r++){
          int m = bm + wrow + mt*16 + quad*4 + r;
          int n = bn + wcol + nt*16 + l16;
          float v = acc[mt][nt][r]; v = fmaxf(v, 0.f); v *= v;
          shh[(size_t)m*SI + n] = f2bf(v);
        }
  } else {
    // expert up: hws[slot][512] = bf16(relu2(x_t . up_e^T) * w)
    int eu = blk - 256;
    int pv = plan[1 + (eu >> 2)];
    if (pv < 0) return;
    int e = pv & 255;
    int tb = pv >> 8;
    int c = cnt[e];
    int bn = (eu & 3) * 128;
    const int* tl = tok + e * T_TOK;
    const float* wle = wl + e * T_TOK;
    int s0 = tb + srow;      if (s0 > c-1) s0 = c-1;
    int s1 = tb + 64 + srow; if (s1 > c-1) s1 = c-1;
    int t0 = tl[s0] >> 3, t1 = tl[s1] >> 3;
    const char* gA0 = (const char*)(xb + (size_t)t0*HID) + sseg;
    const char* gA1 = (const char*)(xb + (size_t)t1*HID) + sseg;
    const u16* Bb = upb + (size_t)e * IM * HID;
    const char* gB0 = (const char*)(Bb + (size_t)(bn + srow)*HID) + sseg;
    const char* gB1 = (const char*)(Bb + (size_t)(bn + 64 + srow)*HID) + sseg;
    ACC_INIT;
    gemm_core(gA0, gA1, gB0, gB1, lA, lB, HID/32, tid, wrow, wcol, quad, l16, acc);
#pragma unroll
    for (int mt = 0; mt < 4; mt++)
#pragma unroll
      for (int r = 0; r < 4; r++){
        int s = tb + wrow + mt*16 + quad*4 + r;
        if (s < c){
          int code = tl[s];
          float w = wle[s];
          size_t hb = ((size_t)(code >> 3) * TOPK + (code & 7)) * IM;
#pragma unroll
          for (int nt = 0; nt < 4; nt++){
            float v = acc[mt][nt][r]; v = fmaxf(v, 0.f); v = v * v * w;
            hws[hb + bn + wcol + nt*16 + l16] = f2bf(v);
          }
        }
      }
  }
}

// fused B: blocks [0,128) shared-down (64 K-iters, launched first), [128,1408)
// expert-down (16 K-iters). out pre-zeroed; both sides atomicAdd -> no ordering race.
__global__ __launch_bounds__(256) void down_fused_kernel(
    const u16* __restrict__ shh, const u16* __restrict__ sdnb,
    const u16* __restrict__ hws, const u16* __restrict__ dnb,
    const int* __restrict__ cnt, const int* __restrict__ tok, const int* __restrict__ plan,
    float* __restrict__ out){
  __shared__ u16 lA[2*128*32], lB[2*128*32];
  int tid = threadIdx.x;
  int lane = tid & 63, wave = tid >> 6, quad = lane >> 4, l16 = lane & 15;
  int wrow = (wave >> 1)*64, wcol = (wave & 1)*64;
  int srow = tid >> 2, sseg = (tid & 3)*16;
  int blk = blockIdx.x;
  if (blk < 128){
    // shared down: out += H[2048][2048] . sdnW[1024][2048]^T
    int bm = (blk >> 3)*128, bn = (blk & 7)*128;
    const char* gA0 = (const char*)(shh + (size_t)(bm + srow)*SI) + sseg;
    const char* gA1 = (const char*)(shh + (size_t)(bm + 64 + srow)*SI) + sseg;
    const char* gB0 = (const char*)(sdnb + (size_t)(bn + srow)*SI) + sseg;
    const char* gB1 = (const char*)(sdnb + (size_t)(bn + 64 + srow)*SI) + sseg;
    ACC_INIT;
    gemm_core(gA0, gA1, gB0, gB1, lA, lB, SI/32, tid, wrow, wcol, quad, l16, acc);
#pragma unroll
    for (int mt = 0; mt < 4; mt++)
#pragma unroll
      for (int nt = 0; nt < 4; nt++)
#pragma unroll
        for (int r = 0; r < 4; r++){
          int m = bm + wrow + mt*16 + quad*4 + r;
          int n = bn + wcol + nt*16 + l16;
          unsafeAtomicAdd(&out[(size_t)m*HID + n], acc[mt][nt][r]);
        }
  } else {
    // expert down: out[t] += h_slot . down_e^T
    int eu = blk - 128;
    int pv = plan[1 + (eu >> 3)];
    if (pv < 0) return;
    int e = pv & 255;
    int tb = pv >> 8;
    int c = cnt[e];
    int bn = (eu & 7) * 128;
    const int* tl = tok + e * T_TOK;
    int s0 = tb + srow;      if (s0 > c-1) s0 = c-1;
    int s1 = tb + 64 + srow; if (s1 > c-1) s1 = c-1;
    int c0 = tl[s0], c1 = tl[s1];
    const char* gA0 = (const char*)(hws + ((size_t)(c0 >> 3)*TOPK + (c0 & 7))*IM) + sseg;
    const char* gA1 = (const char*)(hws + ((size_t)(c1 >> 3)*TOPK + (c1 & 7))*IM) + sseg;
    const u16* Bb = dnb + (size_t)e * HID * IM;
    const char* gB0 = (const char*)(Bb + (size_t)(bn + srow)*IM) + sseg;
    const char* gB1 = (const char*)(Bb + (size_t)(bn + 64 + srow)*IM) + sseg;
    ACC_INIT;
    gemm_core(gA0, gA1, gB0, gB1, lA, lB, IM/32, tid, wrow, wcol, quad, l16, acc);
#pragma unroll
    for (int mt = 0; mt < 4; mt++)
#pragma unroll
      for (int r = 0; r < 4; r++){
        int s = tb + wrow + mt*16 + quad*4 + r;
        if (s < c){
          int code = tl[s];
          float* ob = out + (size_t)(code >> 3) * HID;
#pragma unroll
          for (int nt = 0; nt < 4; nt++)
            unsafeAtomicAdd(&ob[bn + wcol + nt*16 + l16], acc[mt][nt][r]);
        }
      }
  }
}

extern "C" void kernel_launch(void* const* d_in, const int* in_sizes, int n_in,
                              void* d_out, int out_size, void* d_ws, size_t ws_size,
                              hipStream_t stream) {
  const float* x    = (const float*)d_in[0];
  const float* gate = (const float*)d_in[1];
  const float* eb   = (const float*)d_in[2];
  const float* upw  = (const float*)d_in[3];
  const float* dnw  = (const float*)d_in[4];
  const float* supw = (const float*)d_in[5];
  const float* sdnw = (const float*)d_in[6];
  float* out = (float*)d_out;

  char* w = (char*)d_ws;
  size_t o = 0;
  int*   cnt  = (int*)(w + o);   o += 1024;
  int*   plan = (int*)(w + o);   o += 1024;
  int*   ce   = (int*)(w + o);   o += (size_t)T_TOK * TOPK * 4;
  float* cw   = (float*)(w + o); o += (size_t)T_TOK * TOPK * 4;
  int*   tok  = (int*)(w + o);   o += (size_t)NEXP * T_TOK * 4;
  float* wl   = (float*)(w + o); o += (size_t)NEXP * T_TOK * 4;
  u16*   xb   = (u16*)(w + o);   o += (size_t)T_TOK * HID * 2;
  u16*   dnb  = (u16*)(w + o);   o += (size_t)NEXP * HID * IM * 2;
  u16*   hws  = (u16*)(w + o);   o += (size_t)T_TOK * TOPK * IM * 2;
  u16*   upb  = (u16*)(w + o);   o += (size_t)NEXP * IM * HID * 2;
  u16*   supb = (u16*)(w + o);   o += (size_t)SI * HID * 2;
  u16*   sdnb = (u16*)(w + o);   o += (size_t)HID * SI * 2;
  u16*   shh  = (u16*)(w + o);   o += (size_t)T_TOK * SI * 2;

  cvt_big_kernel<<<16384, 256, 0, stream>>>(
      (const float4*)upw, (const float4*)dnw, (u16x8*)upb, (u16x8*)dnb);
  cvt_small_router_kernel<<<3584, 256, 0, stream>>>(
      x, (const float4*)supw, (const float4*)sdnw, gate, eb,
      (u16x8*)xb, (u16x8*)supb, (u16x8*)sdnb, ce, cw);
  build_kernel<<<NEXP, 256, 0, stream>>>(ce, cw, cnt, tok, wl);
  plan_kernel<<<1, 256, 0, stream>>>(cnt, plan);

  up_fused_kernel<<<896, 256, 0, stream>>>(xb, supb, upb, cnt, tok, wl, plan, shh, hws);
  hipMemsetAsync(out, 0, (size_t)T_TOK * HID * 4, stream);
  down_fused_kernel<<<1408, 256, 0, stream>>>(shh, sdnb, hws, dnb, cnt, tok, plan, out);
}

// Round 3
// 360.008 us; speedup vs baseline: 1.1311x; 1.0267x over previous
//
#include <hip/hip_runtime.h>

typedef unsigned short u16;
typedef __bf16 bf16x8 __attribute__((ext_vector_type(8)));
typedef float f32x4 __attribute__((ext_vector_type(4)));
typedef u16 u16x8 __attribute__((ext_vector_type(8)));

#define T_TOK 2048
#define HID   1024
#define NEXP  32
#define IM    512
#define SI    2048
#define TOPK  6
#define PLAN_MAX 160

// exact RNE float->bf16
__device__ __forceinline__ u16 f2bf(float f){
  unsigned u = __float_as_uint(f);
  u += 0x7FFFu + ((u >> 16) & 1u);
  return (u16)(u >> 16);
}

// async global->LDS, 16B per lane. LDS dest must be wave-uniform base + lane*16.
__device__ __forceinline__ void gll16(const void* g, void* l){
  __builtin_amdgcn_global_load_lds((const __attribute__((address_space(1))) void*)g,
                                   (__attribute__((address_space(3))) void*)l, 16, 0, 0);
}

__device__ __forceinline__ u16x8 cvt2(float4 a, float4 b){
  u16x8 o;
  o[0] = f2bf(a.x); o[1] = f2bf(a.y); o[2] = f2bf(a.z); o[3] = f2bf(a.w);
  o[4] = f2bf(b.x); o[5] = f2bf(b.y); o[6] = f2bf(b.z); o[7] = f2bf(b.w);
  return o;
}

// one prep kernel: router (blocks 0..511) + big cvt upw|dnw (512..16895) +
// small cvt x|supw|sdnw (16896..19967). Also zeroes the build-done counter.
__global__ __launch_bounds__(256) void prep_kernel(
    const float* __restrict__ x, const float4* __restrict__ upw, const float4* __restrict__ dnw,
    const float4* __restrict__ supw, const float4* __restrict__ sdnw,
    const float* __restrict__ gate, const float* __restrict__ ebias,
    u16x8* __restrict__ xb, u16x8* __restrict__ upb, u16x8* __restrict__ dnb,
    u16x8* __restrict__ supb, u16x8* __restrict__ sdnb,
    int* __restrict__ ce, float* __restrict__ cw, int* __restrict__ done){
  int blk = blockIdx.x;
  if (blk == 0 && threadIdx.x == 0) *done = 0;
  if (blk >= 512){
    const float4* s; u16x8* d; long i;
    if (blk < 16896){
      i = (long)(blk - 512) * 256 + threadIdx.x;
      if (i < 2097152L){ s = upw; d = upb; }
      else             { s = dnw; d = dnb; i -= 2097152L; }
    } else {
      i = (long)(blk - 16896) * 256 + threadIdx.x;
      if      (i < 262144L){ s = (const float4*)x; d = xb; }
      else if (i < 524288L){ s = supw; d = supb; i -= 262144L; }
      else                 { s = sdnw; d = sdnb; i -= 524288L; }
    }
    float4 a = s[2*i], b = s[2*i+1];
    d[i] = cvt2(a, b);
    return;
  }
  // ---- router: 4 tokens/block, 1 wave/token, register cross-lane top-k ----
  int wave = threadIdx.x >> 6;
  int lane = threadIdx.x & 63;
  int t = blk * 4 + wave;
  int e = lane & 31, half = lane >> 5;
  const float4* xv = (const float4*)(x + (size_t)t * HID);
  const float4* gv = (const float4*)(gate + (size_t)e * HID);
  double d0a = 0, d1a = 0, d2a = 0, d3a = 0;
  for (int i = half * 128; i < half * 128 + 128; i++){
    float4 a = xv[i], b = gv[i];
    d0a += (double)a.x * b.x; d1a += (double)a.y * b.y;
    d2a += (double)a.z * b.z; d3a += (double)a.w * b.w;
  }
  double acc = (d0a + d1a) + (d2a + d3a);
  acc += __shfl_xor(acc, 32);
  double score = 1.0 / (1.0 + exp(-acc));
  double sc = score + (double)ebias[e];
  double o1  = __shfl_xor(sc, 1);
  double hi  = fmax(sc, o1), lo = fmin(sc, o1);
  double ohi = __shfl_xor(hi, 2), olo = __shfl_xor(lo, 2);
  double gs  = (hi >= ohi) ? hi + fmax(lo, ohi) : ohi + fmax(olo, hi);
  int g = e >> 2;
  int rank = 0;
#pragma unroll
  for (int j = 0; j < 8; j++){
    double gj = __shfl(gs, j * 4);
    if (gj > gs || (gj == gs && j < g)) rank++;
  }
  double cur = (rank < 4) ? sc : 0.0;
  int sel_e[TOPK]; double sel_w[TOPK]; double wsum = 0.0;
#pragma unroll
  for (int k = 0; k < TOPK; k++){
    double bv = cur; int bi = lane;
#pragma unroll
    for (int m = 32; m >= 1; m >>= 1){
      double ov = __shfl_xor(bv, m); int oi = __shfl_xor(bi, m);
      if (ov > bv || (ov == bv && oi < bi)) { bv = ov; bi = oi; }
    }
    if ((bi & 31) == e) cur = -1e300;
    double ws = __shfl(score, bi);
    sel_e[k] = bi; sel_w[k] = ws; wsum += ws;
  }
  double scale = 2.5 / (wsum + 1e-20);
#pragma unroll
  for (int k = 0; k < TOPK; k++){
    if (lane == k){                       // compile-time idx -> no scratch spill
      ce[t * TOPK + k] = sel_e[k] & 31;
      cw[t * TOPK + k] = (float)(sel_w[k] * scale);
    }
  }
}

// 32 blocks (one per expert): ordered compaction via ballot prefix scan.
// Last-arriving block (atomic counter, all 32 blocks instantly resident) builds
// the dense tile plan: plan[1+i] = (tile_base<<8)|expert per active 128-tile.
__global__ __launch_bounds__(256) void build_plan_kernel(const int* __restrict__ ce,
                                                         const float* __restrict__ cw,
                                                         int* __restrict__ cnt,
                                                         int* __restrict__ tok,
                                                         float* __restrict__ wl,
                                                         int* __restrict__ done,
                                                         int* __restrict__ plan){
  int e = blockIdx.x;
  int tid = threadIdx.x, lane = tid & 63, wave = tid >> 6;
  __shared__ int wsum[4];
  __shared__ int lastflag;
  int running = 0;
  for (int base = 0; base < T_TOK * TOPK; base += 256){
    int i = base + tid;                       // 12288 = 48*256, no bounds check
    bool m = (ce[i] == e);
    unsigned long long bal = __ballot(m);
    int woff = __popcll(bal & ((1ull << lane) - 1ull));
    if (lane == 0) wsum[wave] = __popcll(bal);
    __syncthreads();
    int wbase = 0;
#pragma unroll
    for (int wv = 0; wv < 4; wv++) if (wv < wave) wbase += wsum[wv];
    int btot = wsum[0] + wsum[1] + wsum[2] + wsum[3];
    if (m){
      int t = i / TOPK, k = i - t * TOPK;
      int pos = running + wbase + woff;
      tok[e * T_TOK + pos] = (t << 3) | k;
      wl[e * T_TOK + pos] = cw[i];
    }
    running += btot;
    __syncthreads();                          // wsum WAR hazard for next iter
  }
  if (tid == 0){
    atomicExch(&cnt[e], running);             // write-through, device-visible
    __threadfence();
    lastflag = (atomicAdd(done, 1) == NEXP - 1);
  }
  __syncthreads();
  if (lastflag){
    __threadfence();                          // acquire: other blocks' cnt visible
    if (tid < PLAN_MAX) plan[1 + tid] = -1;
    __syncthreads();
    if (tid == 0){
      int n = 0;
      for (int ee = 0; ee < NEXP; ee++){
        int c = (ee == e) ? running : cnt[ee];
        for (int tb = 0; tb < c; tb += 128) plan[1 + n++] = (tb << 8) | ee;
      }
      plan[0] = n;
    }
  }
}

// ---- 128x128 tile, BK=32, double-buffered LDS (2-phase prefetch).
// LDS bank-conflict fix (rule #21: gll16 dest must stay linear): the global
// SOURCE 16B-segment is XOR-permuted per row at staging (seg ^= (row>>1)&3) and
// fragment reads use qsw = quad ^ ((l16>>1)&3) -> per-16-lane-phase start banks
// {0,16,4,20,8,24,12,28}x2 = balanced 2-way (free) instead of 8-way.
__device__ __forceinline__ void gemm_core(
    const char* gA0, const char* gA1, const char* gB0, const char* gB1,
    u16* lA, u16* lB, int iters, int tid, int wrow, int wcol, int qsw, int l16,
    f32x4 acc[4][4])
{
  char* bA = (char*)lA + tid*16;
  char* bB = (char*)lB + tid*16;
  // prologue: stage tile 0 into buffer 0
  gll16(gA0, bA);  gll16(gA1, bA + 4096);
  gll16(gB0, bB);  gll16(gB1, bB + 4096);
  gA0 += 64; gA1 += 64; gB0 += 64; gB1 += 64;
  __syncthreads();
  unsigned cur = 0;
  for (int it = 0; it < iters - 1; ++it){
    unsigned nxt = cur ^ 1;
    // prefetch next K-tile (in flight during this tile's compute)
    gll16(gA0, bA + nxt*8192);  gll16(gA1, bA + nxt*8192 + 4096);
    gll16(gB0, bB + nxt*8192);  gll16(gB1, bB + nxt*8192 + 4096);
    gA0 += 64; gA1 += 64; gB0 += 64; gB1 += 64;
    const u16* rA = lA + cur*4096;
    const u16* rB = lB + cur*4096;
    bf16x8 af[4], bfr[4];
#pragma unroll
    for (int mt = 0; mt < 4; mt++) af[mt]  = *(const bf16x8*)&rA[(wrow + mt*16 + l16)*32 + qsw*8];
#pragma unroll
    for (int nt = 0; nt < 4; nt++) bfr[nt] = *(const bf16x8*)&rB[(wcol + nt*16 + l16)*32 + qsw*8];
#pragma unroll
    for (int mt = 0; mt < 4; mt++)
#pragma unroll
      for (int nt = 0; nt < 4; nt++)
        acc[mt][nt] = __builtin_amdgcn_mfma_f32_16x16x32_bf16(af[mt], bfr[nt], acc[mt][nt], 0, 0, 0);
    __syncthreads();          // drains prefetch vmcnt + protects buf reuse
    cur = nxt;
  }
  const u16* rA = lA + cur*4096;
  const u16* rB = lB + cur*4096;
  bf16x8 af[4], bfr[4];
#pragma unroll
  for (int mt = 0; mt < 4; mt++) af[mt]  = *(const bf16x8*)&rA[(wrow + mt*16 + l16)*32 + qsw*8];
#pragma unroll
  for (int nt = 0; nt < 4; nt++) bfr[nt] = *(const bf16x8*)&rB[(wcol + nt*16 + l16)*32 + qsw*8];
#pragma unroll
  for (int mt = 0; mt < 4; mt++)
#pragma unroll
    for (int nt = 0; nt < 4; nt++)
      acc[mt][nt] = __builtin_amdgcn_mfma_f32_16x16x32_bf16(af[mt], bfr[nt], acc[mt][nt], 0, 0, 0);
}

#define ACC_INIT f32x4 acc[4][4]; \
  _Pragma("unroll") for (int i_ = 0; i_ < 4; i_++) \
  _Pragma("unroll") for (int j_ = 0; j_ < 4; j_++) acc[i_][j_] = (f32x4){0.f,0.f,0.f,0.f};

#define GEO_INIT int tid = threadIdx.x; \
  int lane = tid & 63, wave = tid >> 6, quad = lane >> 4, l16 = lane & 15; \
  int wrow = (wave >> 1)*64, wcol = (wave & 1)*64; \
  int srow = tid >> 2; \
  int sseg = ((tid & 3) ^ ((tid >> 3) & 3)) * 16; \
  int qsw  = quad ^ ((l16 >> 1) & 3);

// fused A: blocks [0,256) shared-up, [256,896) expert-up. All 32 K-iters.
__global__ __launch_bounds__(256) void up_fused_kernel(
    const u16* __restrict__ xb, const u16* __restrict__ supb, const u16* __restrict__ upb,
    const int* __restrict__ cnt, const int* __restrict__ tok, const float* __restrict__ wl,
    const int* __restrict__ plan, u16* __restrict__ shh, u16* __restrict__ hws){
  __shared__ u16 lA[2*128*32], lB[2*128*32];
  GEO_INIT;
  int blk = blockIdx.x;
  if (blk < 256){
    // shared up: shh[2048][2048] = bf16(relu2(X . supW^T))
    int bm = (blk >> 4) * 128, bn = (blk & 15) * 128;
    const char* gA0 = (const char*)(xb + (size_t)(bm + srow)*HID) + sseg;
    const char* gA1 = (const char*)(xb + (size_t)(bm + 64 + srow)*HID) + sseg;
    const char* gB0 = (const char*)(supb + (size_t)(bn + srow)*HID) + sseg;
    const char* gB1 = (const char*)(supb + (size_t)(bn + 64 + srow)*HID) + sseg;
    ACC_INIT;
    gemm_core(gA0, gA1, gB0, gB1, lA, lB, HID/32, tid, wrow, wcol, qsw, l16, acc);
#pragma unroll
    for (int mt = 0; mt < 4; mt++)
#pragma unroll
      for (int nt = 0; nt < 4; nt++)
#pragma unroll
        for (int r = 0; r < 4; r++){
          int m = bm + wrow + mt*16 + quad*4 + r;
          int n = bn + wcol + nt*16 + l16;
          float v = acc[mt][nt][r]; v = fmaxf(v, 0.f); v *= v;
          shh[(size_t)m*SI + n] = f2bf(v);
        }
  } else {
    // expert up: hws[slot][512] = bf16(relu2(x_t . up_e^T) * w)
    int eu = blk - 256;
    int pv = plan[1 + (eu >> 2)];
    if (pv < 0) return;
    int e = pv & 255;
    int tb = pv >> 8;
    int c = cnt[e];
    int bn = (eu & 3) * 128;
    const int* tl = tok + e * T_TOK;
    const float* wle = wl + e * T_TOK;
    int s0 = tb + srow;      if (s0 > c-1) s0 = c-1;
    int s1 = tb + 64 + srow; if (s1 > c-1) s1 = c-1;
    int t0 = tl[s0] >> 3, t1 = tl[s1] >> 3;
    const char* gA0 = (const char*)(xb + (size_t)t0*HID) + sseg;
    const char* gA1 = (const char*)(xb + (size_t)t1*HID) + sseg;
    const u16* Bb = upb + (size_t)e * IM * HID;
    const char* gB0 = (const char*)(Bb + (size_t)(bn + srow)*HID) + sseg;
    const char* gB1 = (const char*)(Bb + (size_t)(bn + 64 + srow)*HID) + sseg;
    ACC_INIT;
    gemm_core(gA0, gA1, gB0, gB1, lA, lB, HID/32, tid, wrow, wcol, qsw, l16, acc);
#pragma unroll
    for (int mt = 0; mt < 4; mt++)
#pragma unroll
      for (int r = 0; r < 4; r++){
        int s = tb + wrow + mt*16 + quad*4 + r;
        if (s < c){
          int code = tl[s];
          float w = wle[s];
          size_t hb = ((size_t)(code >> 3) * TOPK + (code & 7)) * IM;
#pragma unroll
          for (int nt = 0; nt < 4; nt++){
            float v = acc[mt][nt][r]; v = fmaxf(v, 0.f); v = v * v * w;
            hws[hb + bn + wcol + nt*16 + l16] = f2bf(v);
          }
        }
      }
  }
}

// fused B: blocks [0,512) shared-down K-split 4x (each block 16 K-iters, partial
// sums atomically added), [512,1792) expert-down (16 K-iters). Every block has
// identical length -> no half-idle tail. out pre-zeroed; all writers atomic.
__global__ __launch_bounds__(256) void down_fused_kernel(
    const u16* __restrict__ shh, const u16* __restrict__ sdnb,
    const u16* __restrict__ hws, const u16* __restrict__ dnb,
    const int* __restrict__ cnt, const int* __restrict__ tok, const int* __restrict__ plan,
    float* __restrict__ out){
  __shared__ u16 lA[2*128*32], lB[2*128*32];
  GEO_INIT;
  int blk = blockIdx.x;
  if (blk < 512){
    // shared down partial: out += H[bm:,kc*512:(kc+1)*512] . sdnW[bn:,same]^T
    int kc = blk & 3;
    int bn = ((blk >> 2) & 7) * 128;
    int bm = (blk >> 5) * 128;
    const char* gA0 = (const char*)(shh + (size_t)(bm + srow)*SI + kc*512) + sseg;
    const char* gA1 = (const char*)(shh + (size_t)(bm + 64 + srow)*SI + kc*512) + sseg;
    const char* gB0 = (const char*)(sdnb + (size_t)(bn + srow)*SI + kc*512) + sseg;
    const char* gB1 = (const char*)(sdnb + (size_t)(bn + 64 + srow)*SI + kc*512) + sseg;
    ACC_INIT;
    gemm_core(gA0, gA1, gB0, gB1, lA, lB, 16, tid, wrow, wcol, qsw, l16, acc);
#pragma unroll
    for (int mt = 0; mt < 4; mt++)
#pragma unroll
      for (int nt = 0; nt < 4; nt++)
#pragma unroll
        for (int r = 0; r < 4; r++){
          int m = bm + wrow + mt*16 + quad*4 + r;
          int n = bn + wcol + nt*16 + l16;
          unsafeAtomicAdd(&out[(size_t)m*HID + n], acc[mt][nt][r]);
        }
  } else {
    // expert down: out[t] += h_slot . down_e^T
    int eu = blk - 512;
    int pv = plan[1 + (eu >> 3)];
    if (pv < 0) return;
    int e = pv & 255;
    int tb = pv >> 8;
    int c = cnt[e];
    int bn = (eu & 7) * 128;
    const int* tl = tok + e * T_TOK;
    int s0 = tb + srow;      if (s0 > c-1) s0 = c-1;
    int s1 = tb + 64 + srow; if (s1 > c-1) s1 = c-1;
    int c0 = tl[s0], c1 = tl[s1];
    const char* gA0 = (const char*)(hws + ((size_t)(c0 >> 3)*TOPK + (c0 & 7))*IM) + sseg;
    const char* gA1 = (const char*)(hws + ((size_t)(c1 >> 3)*TOPK + (c1 & 7))*IM) + sseg;
    const u16* Bb = dnb + (size_t)e * HID * IM;
    const char* gB0 = (const char*)(Bb + (size_t)(bn + srow)*IM) + sseg;
    const char* gB1 = (const char*)(Bb + (size_t)(bn + 64 + srow)*IM) + sseg;
    ACC_INIT;
    gemm_core(gA0, gA1, gB0, gB1, lA, lB, IM/32, tid, wrow, wcol, qsw, l16, acc);
#pragma unroll
    for (int mt = 0; mt < 4; mt++)
#pragma unroll
      for (int r = 0; r < 4; r++){
        int s = tb + wrow + mt*16 + quad*4 + r;
        if (s < c){
          int code = tl[s];
          float* ob = out + (size_t)(code >> 3) * HID;
#pragma unroll
          for (int nt = 0; nt < 4; nt++)
            unsafeAtomicAdd(&ob[bn + wcol + nt*16 + l16], acc[mt][nt][r]);
        }
      }
  }
}

extern "C" void kernel_launch(void* const* d_in, const int* in_sizes, int n_in,
                              void* d_out, int out_size, void* d_ws, size_t ws_size,
                              hipStream_t stream) {
  const float* x    = (const float*)d_in[0];
  const float* gate = (const float*)d_in[1];
  const float* eb   = (const float*)d_in[2];
  const float* upw  = (const float*)d_in[3];
  const float* dnw  = (const float*)d_in[4];
  const float* supw = (const float*)d_in[5];
  const float* sdnw = (const float*)d_in[6];
  float* out = (float*)d_out;

  char* w = (char*)d_ws;
  size_t o = 0;
  int*   cnt  = (int*)(w + o);   o += 1024;
  int*   plan = (int*)(w + o);   o += 1024;
  int*   ce   = (int*)(w + o);   o += (size_t)T_TOK * TOPK * 4;
  float* cw   = (float*)(w + o); o += (size_t)T_TOK * TOPK * 4;
  int*   tok  = (int*)(w + o);   o += (size_t)NEXP * T_TOK * 4;
  float* wl   = (float*)(w + o); o += (size_t)NEXP * T_TOK * 4;
  u16*   xb   = (u16*)(w + o);   o += (size_t)T_TOK * HID * 2;
  u16*   dnb  = (u16*)(w + o);   o += (size_t)NEXP * HID * IM * 2;
  u16*   hws  = (u16*)(w + o);   o += (size_t)T_TOK * TOPK * IM * 2;
  u16*   upb  = (u16*)(w + o);   o += (size_t)NEXP * IM * HID * 2;
  u16*   supb = (u16*)(w + o);   o += (size_t)SI * HID * 2;
  u16*   sdnb = (u16*)(w + o);   o += (size_t)HID * SI * 2;
  u16*   shh  = (u16*)(w + o);   o += (size_t)T_TOK * SI * 2;
  int*   done = cnt + 32;        // lives in cnt's padding

  hipMemsetAsync(out, 0, (size_t)T_TOK * HID * 4, stream);
  prep_kernel<<<19968, 256, 0, stream>>>(
      x, (const float4*)upw, (const float4*)dnw, (const float4*)supw, (const float4*)sdnw,
      gate, eb, (u16x8*)xb, (u16x8*)upb, (u16x8*)dnb, (u16x8*)supb, (u16x8*)sdnb,
      ce, cw, done);
  build_plan_kernel<<<NEXP, 256, 0, stream>>>(ce, cw, cnt, tok, wl, done, plan);
  up_fused_kernel<<<896, 256, 0, stream>>>(xb, supb, upb, cnt, tok, wl, plan, shh, hws);
  down_fused_kernel<<<1792, 256, 0, stream>>>(shh, sdnb, hws, dnb, cnt, tok, plan, out);
}

// Round 5
// 335.655 us; speedup vs baseline: 1.2131x; 1.0726x over previous
//
#include <hip/hip_runtime.h>

typedef unsigned short u16;
typedef __bf16 bf16x8 __attribute__((ext_vector_type(8)));
typedef float f32x4 __attribute__((ext_vector_type(4)));
typedef u16 u16x8 __attribute__((ext_vector_type(8)));

#define T_TOK 2048
#define HID   1024
#define NEXP  32
#define IM    512
#define SI    2048
#define TOPK  6
#define PLAN_MAX 160

// exact RNE float->bf16
__device__ __forceinline__ u16 f2bf(float f){
  unsigned u = __float_as_uint(f);
  u += 0x7FFFu + ((u >> 16) & 1u);
  return (u16)(u >> 16);
}

// async global->LDS, 16B per lane. LDS dest must be wave-uniform base + lane*16.
__device__ __forceinline__ void gll16(const void* g, void* l){
  __builtin_amdgcn_global_load_lds((const __attribute__((address_space(1))) void*)g,
                                   (__attribute__((address_space(3))) void*)l, 16, 0, 0);
}

__device__ __forceinline__ u16x8 cvt2(float4 a, float4 b){
  u16x8 o;
  o[0] = f2bf(a.x); o[1] = f2bf(a.y); o[2] = f2bf(a.z); o[3] = f2bf(a.w);
  o[4] = f2bf(b.x); o[5] = f2bf(b.y); o[6] = f2bf(b.z); o[7] = f2bf(b.w);
  return o;
}

// one prep kernel: router (blocks 0..511) + big cvt upw|dnw (512..16895) +
// small cvt x|supw|sdnw (16896..19967). Also zeroes the build-done counter.
__global__ __launch_bounds__(256) void prep_kernel(
    const float* __restrict__ x, const float4* __restrict__ upw, const float4* __restrict__ dnw,
    const float4* __restrict__ supw, const float4* __restrict__ sdnw,
    const float* __restrict__ gate, const float* __restrict__ ebias,
    u16x8* __restrict__ xb, u16x8* __restrict__ upb, u16x8* __restrict__ dnb,
    u16x8* __restrict__ supb, u16x8* __restrict__ sdnb,
    int* __restrict__ ce, float* __restrict__ cw, int* __restrict__ done){
  int blk = blockIdx.x;
  if (blk == 0 && threadIdx.x == 0) *done = 0;
  if (blk >= 512){
    const float4* s; u16x8* d; long i;
    if (blk < 16896){
      i = (long)(blk - 512) * 256 + threadIdx.x;
      if (i < 2097152L){ s = upw; d = upb; }
      else             { s = dnw; d = dnb; i -= 2097152L; }
    } else {
      i = (long)(blk - 16896) * 256 + threadIdx.x;
      if      (i < 262144L){ s = (const float4*)x; d = xb; }
      else if (i < 524288L){ s = supw; d = supb; i -= 262144L; }
      else                 { s = sdnw; d = sdnb; i -= 524288L; }
    }
    float4 a = s[2*i], b = s[2*i+1];
    d[i] = cvt2(a, b);
    return;
  }
  // ---- router: 4 tokens/block, 1 wave/token, register cross-lane top-k ----
  int wave = threadIdx.x >> 6;
  int lane = threadIdx.x & 63;
  int t = blk * 4 + wave;
  int e = lane & 31, half = lane >> 5;
  const float4* xv = (const float4*)(x + (size_t)t * HID);
  const float4* gv = (const float4*)(gate + (size_t)e * HID);
  double d0a = 0, d1a = 0, d2a = 0, d3a = 0;
  for (int i = half * 128; i < half * 128 + 128; i++){
    float4 a = xv[i], b = gv[i];
    d0a += (double)a.x * b.x; d1a += (double)a.y * b.y;
    d2a += (double)a.z * b.z; d3a += (double)a.w * b.w;
  }
  double acc = (d0a + d1a) + (d2a + d3a);
  acc += __shfl_xor(acc, 32);
  double score = 1.0 / (1.0 + exp(-acc));
  double sc = score + (double)ebias[e];
  double o1  = __shfl_xor(sc, 1);
  double hi  = fmax(sc, o1), lo = fmin(sc, o1);
  double ohi = __shfl_xor(hi, 2), olo = __shfl_xor(lo, 2);
  double gs  = (hi >= ohi) ? hi + fmax(lo, ohi) : ohi + fmax(olo, hi);
  int g = e >> 2;
  int rank = 0;
#pragma unroll
  for (int j = 0; j < 8; j++){
    double gj = __shfl(gs, j * 4);
    if (gj > gs || (gj == gs && j < g)) rank++;
  }
  double cur = (rank < 4) ? sc : 0.0;
  int sel_e[TOPK]; double sel_w[TOPK]; double wsum = 0.0;
#pragma unroll
  for (int k = 0; k < TOPK; k++){
    double bv = cur; int bi = lane;
#pragma unroll
    for (int m = 32; m >= 1; m >>= 1){
      double ov = __shfl_xor(bv, m); int oi = __shfl_xor(bi, m);
      if (ov > bv || (ov == bv && oi < bi)) { bv = ov; bi = oi; }
    }
    if ((bi & 31) == e) cur = -1e300;
    double ws = __shfl(score, bi);
    sel_e[k] = bi; sel_w[k] = ws; wsum += ws;
  }
  double scale = 2.5 / (wsum + 1e-20);
#pragma unroll
  for (int k = 0; k < TOPK; k++){
    if (lane == k){                       // compile-time idx -> no scratch spill
      ce[t * TOPK + k] = sel_e[k] & 31;
      cw[t * TOPK + k] = (float)(sel_w[k] * scale);
    }
  }
}

// 32 blocks (one per expert): ordered compaction via ballot prefix scan.
// Last-arriving block builds the dense tile plan.
__global__ __launch_bounds__(256) void build_plan_kernel(const int* __restrict__ ce,
                                                         const float* __restrict__ cw,
                                                         int* __restrict__ cnt,
                                                         int* __restrict__ tok,
                                                         float* __restrict__ wl,
                                                         int* __restrict__ done,
                                                         int* __restrict__ plan){
  int e = blockIdx.x;
  int tid = threadIdx.x, lane = tid & 63, wave = tid >> 6;
  __shared__ int wsum[4];
  __shared__ int lastflag;
  int running = 0;
  for (int base = 0; base < T_TOK * TOPK; base += 256){
    int i = base + tid;                       // 12288 = 48*256, no bounds check
    bool m = (ce[i] == e);
    unsigned long long bal = __ballot(m);
    int woff = __popcll(bal & ((1ull << lane) - 1ull));
    if (lane == 0) wsum[wave] = __popcll(bal);
    __syncthreads();
    int wbase = 0;
#pragma unroll
    for (int wv = 0; wv < 4; wv++) if (wv < wave) wbase += wsum[wv];
    int btot = wsum[0] + wsum[1] + wsum[2] + wsum[3];
    if (m){
      int t = i / TOPK, k = i - t * TOPK;
      int pos = running + wbase + woff;
      tok[e * T_TOK + pos] = (t << 3) | k;
      wl[e * T_TOK + pos] = cw[i];
    }
    running += btot;
    __syncthreads();                          // wsum WAR hazard for next iter
  }
  if (tid == 0){
    atomicExch(&cnt[e], running);             // write-through, device-visible
    __threadfence();
    lastflag = (atomicAdd(done, 1) == NEXP - 1);
  }
  __syncthreads();
  if (lastflag){
    __threadfence();                          // acquire: other blocks' cnt visible
    if (tid < PLAN_MAX) plan[1 + tid] = -1;
    __syncthreads();
    if (tid == 0){
      int n = 0;
      for (int ee = 0; ee < NEXP; ee++){
        int c = (ee == e) ? running : cnt[ee];
        for (int tb = 0; tb < c; tb += 128) plan[1 + n++] = (tb << 8) | ee;
      }
      plan[0] = n;
    }
  }
}

// ---- 128x128 tile, BK=32, 3-buffer pipeline with COUNTED vmcnt (T4): loads for
// the next 2 K-tiles stay in flight ACROSS the barriers (never drain to 0 in the
// main loop) -> ~2-iter latency tolerance instead of the 2-phase full-drain stall.
// Source 16B-segment swizzle (seg ^= (row>>1)&3) keeps ds_read_b128 conflict-free
// while the gll16 LDS dest stays linear (rule #21).
__device__ __forceinline__ void gemm_pipe(
    const char* gA0, const char* gA1, const char* gB0, const char* gB1,
    u16* lA, u16* lB, int iters, int tid, int wrow, int wcol, int qsw, int l16,
    f32x4 acc[4][4])
{
  char* bA = (char*)lA + tid*16;
  char* bB = (char*)lB + tid*16;
#define STAGE(t, b) do { \
    gll16(gA0 + (size_t)(t)*64, bA + (b)*8192); \
    gll16(gA1 + (size_t)(t)*64, bA + (b)*8192 + 4096); \
    gll16(gB0 + (size_t)(t)*64, bB + (b)*8192); \
    gll16(gB1 + (size_t)(t)*64, bB + (b)*8192 + 4096); } while(0)
#define COMPUTE(rbuf) do { \
    const u16* rA = lA + (rbuf)*4096; \
    const u16* rB = lB + (rbuf)*4096; \
    bf16x8 af[4], bfr[4]; \
    _Pragma("unroll") \
    for (int mt = 0; mt < 4; mt++) af[mt]  = *(const bf16x8*)&rA[(wrow + mt*16 + l16)*32 + qsw*8]; \
    _Pragma("unroll") \
    for (int nt = 0; nt < 4; nt++) bfr[nt] = *(const bf16x8*)&rB[(wcol + nt*16 + l16)*32 + qsw*8]; \
    _Pragma("unroll") \
    for (int mt = 0; mt < 4; mt++) \
    _Pragma("unroll") \
      for (int nt = 0; nt < 4; nt++) \
        acc[mt][nt] = __builtin_amdgcn_mfma_f32_16x16x32_bf16(af[mt], bfr[nt], acc[mt][nt], 0, 0, 0); \
    } while(0)

  STAGE(0, 0); STAGE(1, 1);
  int rb = 0, sb = 2;
  for (int it = 0; it < iters - 2; ++it){
    STAGE(it + 2, sb);
    asm volatile("s_waitcnt vmcnt(8)" ::: "memory");   // own T(it) landed; T(it+1),T(it+2) in flight
    __builtin_amdgcn_s_barrier();                      // all waves' T(it) landed
    asm volatile("" ::: "memory");
    COMPUTE(rb);
    asm volatile("" ::: "memory");
    __builtin_amdgcn_s_barrier();                      // reads of buf rb done -> may be restaged
    asm volatile("" ::: "memory");
    rb = (rb + 1 == 3) ? 0 : rb + 1;
    sb = (sb + 1 == 3) ? 0 : sb + 1;
  }
  asm volatile("s_waitcnt vmcnt(4)" ::: "memory");
  __builtin_amdgcn_s_barrier();
  asm volatile("" ::: "memory");
  COMPUTE(rb);
  asm volatile("" ::: "memory");
  __builtin_amdgcn_s_barrier();
  asm volatile("" ::: "memory");
  rb = (rb + 1 == 3) ? 0 : rb + 1;
  asm volatile("s_waitcnt vmcnt(0)" ::: "memory");
  __builtin_amdgcn_s_barrier();
  asm volatile("" ::: "memory");
  COMPUTE(rb);
#undef STAGE
#undef COMPUTE
}

#define ACC_INIT f32x4 acc[4][4]; \
  _Pragma("unroll") for (int i_ = 0; i_ < 4; i_++) \
  _Pragma("unroll") for (int j_ = 0; j_ < 4; j_++) acc[i_][j_] = (f32x4){0.f,0.f,0.f,0.f};

#define GEO_INIT int tid = threadIdx.x; \
  int lane = tid & 63, wave = tid >> 6, quad = lane >> 4, l16 = lane & 15; \
  int wrow = (wave >> 1)*64, wcol = (wave & 1)*64; \
  int srow = tid >> 2; \
  int sseg = ((tid & 3) ^ ((tid >> 3) & 3)) * 16; \
  int qsw  = quad ^ ((l16 >> 1) & 3);

// fused A: blocks [0,256) shared-up, [256,896) expert-up. All 32 K-iters.
__global__ __launch_bounds__(256) void up_fused_kernel(
    const u16* __restrict__ xb, const u16* __restrict__ supb, const u16* __restrict__ upb,
    const int* __restrict__ cnt, const int* __restrict__ tok, const float* __restrict__ wl,
    const int* __restrict__ plan, u16* __restrict__ shh, u16* __restrict__ hws){
  __shared__ u16 lA[3*4096], lB[3*4096];
  GEO_INIT;
  int blk = blockIdx.x;
  if (blk < 256){
    // shared up: shh[2048][2048] = bf16(relu2(X . supW^T))
    int bm = (blk >> 4) * 128, bn = (blk & 15) * 128;
    const char* gA0 = (const char*)(xb + (size_t)(bm + srow)*HID) + sseg;
    const char* gA1 = (const char*)(xb + (size_t)(bm + 64 + srow)*HID) + sseg;
    const char* gB0 = (const char*)(supb + (size_t)(bn + srow)*HID) + sseg;
    const char* gB1 = (const char*)(supb + (size_t)(bn + 64 + srow)*HID) + sseg;
    ACC_INIT;
    gemm_pipe(gA0, gA1, gB0, gB1, lA, lB, HID/32, tid, wrow, wcol, qsw, l16, acc);
#pragma unroll
    for (int mt = 0; mt < 4; mt++)
#pragma unroll
      for (int nt = 0; nt < 4; nt++)
#pragma unroll
        for (int r = 0; r < 4; r++){
          int m = bm + wrow + mt*16 + quad*4 + r;
          int n = bn + wcol + nt*16 + l16;
          float v = acc[mt][nt][r]; v = fmaxf(v, 0.f); v *= v;
          shh[(size_t)m*SI + n] = f2bf(v);
        }
  } else {
    // expert up: hws[slot][512] = bf16(relu2(x_t . up_e^T) * w)
    int eu = blk - 256;
    int pv = plan[1 + (eu >> 2)];
    if (pv < 0) return;
    int e = pv & 255;
    int tb = pv >> 8;
    int c = cnt[e];
    int bn = (eu & 3) * 128;
    const int* tl = tok + e * T_TOK;
    const float* wle = wl + e * T_TOK;
    int s0 = tb + srow;      if (s0 > c-1) s0 = c-1;
    int s1 = tb + 64 + srow; if (s1 > c-1) s1 = c-1;
    int t0 = tl[s0] >> 3, t1 = tl[s1] >> 3;
    const char* gA0 = (const char*)(xb + (size_t)t0*HID) + sseg;
    const char* gA1 = (const char*)(xb + (size_t)t1*HID) + sseg;
    const u16* Bb = upb + (size_t)e * IM * HID;
    const char* gB0 = (const char*)(Bb + (size_t)(bn + srow)*HID) + sseg;
    const char* gB1 = (const char*)(Bb + (size_t)(bn + 64 + srow)*HID) + sseg;
    ACC_INIT;
    gemm_pipe(gA0, gA1, gB0, gB1, lA, lB, HID/32, tid, wrow, wcol, qsw, l16, acc);
#pragma unroll
    for (int mt = 0; mt < 4; mt++)
#pragma unroll
      for (int r = 0; r < 4; r++){
        int s = tb + wrow + mt*16 + quad*4 + r;
        if (s < c){
          int code = tl[s];
          float w = wle[s];
          size_t hb = ((size_t)(code >> 3) * TOPK + (code & 7)) * IM;
#pragma unroll
          for (int nt = 0; nt < 4; nt++){
            float v = acc[mt][nt][r]; v = fmaxf(v, 0.f); v = v * v * w;
            hws[hb + bn + wcol + nt*16 + l16] = f2bf(v);
          }
        }
      }
  }
}

// fused B: blocks [0,128) shared-down (64 K-iters, dispatched first),
// [128,1408) expert-down (16 K-iters). out pre-zeroed; all writers atomic.
__global__ __launch_bounds__(256) void down_fused_kernel(
    const u16* __restrict__ shh, const u16* __restrict__ sdnb,
    const u16* __restrict__ hws, const u16* __restrict__ dnb,
    const int* __restrict__ cnt, const int* __restrict__ tok, const int* __restrict__ plan,
    float* __restrict__ out){
  __shared__ u16 lA[3*4096], lB[3*4096];
  GEO_INIT;
  int blk = blockIdx.x;
  if (blk < 128){
    // shared down: out += H[2048][2048] . sdnW[1024][2048]^T
    int bm = (blk >> 3)*128, bn = (blk & 7)*128;
    const char* gA0 = (const char*)(shh + (size_t)(bm + srow)*SI) + sseg;
    const char* gA1 = (const char*)(shh + (size_t)(bm + 64 + srow)*SI) + sseg;
    const char* gB0 = (const char*)(sdnb + (size_t)(bn + srow)*SI) + sseg;
    const char* gB1 = (const char*)(sdnb + (size_t)(bn + 64 + srow)*SI) + sseg;
    ACC_INIT;
    gemm_pipe(gA0, gA1, gB0, gB1, lA, lB, SI/32, tid, wrow, wcol, qsw, l16, acc);
#pragma unroll
    for (int mt = 0; mt < 4; mt++)
#pragma unroll
      for (int nt = 0; nt < 4; nt++)
#pragma unroll
        for (int r = 0; r < 4; r++){
          int m = bm + wrow + mt*16 + quad*4 + r;
          int n = bn + wcol + nt*16 + l16;
          unsafeAtomicAdd(&out[(size_t)m*HID + n], acc[mt][nt][r]);
        }
  } else {
    // expert down: out[t] += h_slot . down_e^T
    int eu = blk - 128;
    int pv = plan[1 + (eu >> 3)];
    if (pv < 0) return;
    int e = pv & 255;
    int tb = pv >> 8;
    int c = cnt[e];
    int bn = (eu & 7) * 128;
    const int* tl = tok + e * T_TOK;
    int s0 = tb + srow;      if (s0 > c-1) s0 = c-1;
    int s1 = tb + 64 + srow; if (s1 > c-1) s1 = c-1;
    int c0 = tl[s0], c1 = tl[s1];
    const char* gA0 = (const char*)(hws + ((size_t)(c0 >> 3)*TOPK + (c0 & 7))*IM) + sseg;
    const char* gA1 = (const char*)(hws + ((size_t)(c1 >> 3)*TOPK + (c1 & 7))*IM) + sseg;
    const u16* Bb = dnb + (size_t)e * HID * IM;
    const char* gB0 = (const char*)(Bb + (size_t)(bn + srow)*IM) + sseg;
    const char* gB1 = (const char*)(Bb + (size_t)(bn + 64 + srow)*IM) + sseg;
    ACC_INIT;
    gemm_pipe(gA0, gA1, gB0, gB1, lA, lB, IM/32, tid, wrow, wcol, qsw, l16, acc);
#pragma unroll
    for (int mt = 0; mt < 4; mt++)
#pragma unroll
      for (int r = 0; r < 4; r++){
        int s = tb + wrow + mt*16 + quad*4 + r;
        if (s < c){
          int code = tl[s];
          float* ob = out + (size_t)(code >> 3) * HID;
#pragma unroll
          for (int nt = 0; nt < 4; nt++)
            unsafeAtomicAdd(&ob[bn + wcol + nt*16 + l16], acc[mt][nt][r]);
        }
      }
  }
}

extern "C" void kernel_launch(void* const* d_in, const int* in_sizes, int n_in,
                              void* d_out, int out_size, void* d_ws, size_t ws_size,
                              hipStream_t stream) {
  const float* x    = (const float*)d_in[0];
  const float* gate = (const float*)d_in[1];
  const float* eb   = (const float*)d_in[2];
  const float* upw  = (const float*)d_in[3];
  const float* dnw  = (const float*)d_in[4];
  const float* supw = (const float*)d_in[5];
  const float* sdnw = (const float*)d_in[6];
  float* out = (float*)d_out;

  char* w = (char*)d_ws;
  size_t o = 0;
  int*   cnt  = (int*)(w + o);   o += 1024;
  int*   plan = (int*)(w + o);   o += 1024;
  int*   ce   = (int*)(w + o);   o += (size_t)T_TOK * TOPK * 4;
  float* cw   = (float*)(w + o); o += (size_t)T_TOK * TOPK * 4;
  int*   tok  = (int*)(w + o);   o += (size_t)NEXP * T_TOK * 4;
  float* wl   = (float*)(w + o); o += (size_t)NEXP * T_TOK * 4;
  u16*   xb   = (u16*)(w + o);   o += (size_t)T_TOK * HID * 2;
  u16*   dnb  = (u16*)(w + o);   o += (size_t)NEXP * HID * IM * 2;
  u16*   hws  = (u16*)(w + o);   o += (size_t)T_TOK * TOPK * IM * 2;
  u16*   upb  = (u16*)(w + o);   o += (size_t)NEXP * IM * HID * 2;
  u16*   supb = (u16*)(w + o);   o += (size_t)SI * HID * 2;
  u16*   sdnb = (u16*)(w + o);   o += (size_t)HID * SI * 2;
  u16*   shh  = (u16*)(w + o);   o += (size_t)T_TOK * SI * 2;
  int*   done = cnt + 32;        // lives in cnt's padding

  hipMemsetAsync(out, 0, (size_t)T_TOK * HID * 4, stream);
  prep_kernel<<<19968, 256, 0, stream>>>(
      x, (const float4*)upw, (const float4*)dnw, (const float4*)supw, (const float4*)sdnw,
      gate, eb, (u16x8*)xb, (u16x8*)upb, (u16x8*)dnb, (u16x8*)supb, (u16x8*)sdnb,
      ce, cw, done);
  build_plan_kernel<<<NEXP, 256, 0, stream>>>(ce, cw, cnt, tok, wl, done, plan);
  up_fused_kernel<<<896, 256, 0, stream>>>(xb, supb, upb, cnt, tok, wl, plan, shh, hws);
  down_fused_kernel<<<1408, 256, 0, stream>>>(shh, sdnb, hws, dnb, cnt, tok, plan, out);
}